// Round 4
// baseline (339.199 us; speedup 1.0000x reference)
//
#include <hip/hip_runtime.h>
#include <hip/hip_bf16.h>
#include <stdint.h>

// NeiAttention: B=512, N=32, S=16, EF=64, NF=D=128, K=192. Tiles = B*N = 16384.
// Block = 256 thr = 4 waves, all on ONE tile; wave wv owns d-rows [32wv,32wv+32).
// W A-frags register-resident: 48 VGPR/lane (2 dt x 6 q) -- fits, no spill.
// feat loaded DIRECTLY from global in B-frag layout (no LDS staging), packed
// cvt to bf16, 12 MFMA/wave. One barrier/tile, double-buffered LDS epilogue.

typedef __attribute__((ext_vector_type(8))) short short8;
typedef __attribute__((ext_vector_type(4))) float float4_t;

#define NBLK 2048
#define TILES_PER_BLK 8   // 2048 * 8 = 16384

__device__ __forceinline__ uint32_t pk2bf(float a, float b) {
    __hip_bfloat162 h = __float22bfloat162_rn(float2{a, b});
    union { __hip_bfloat162 h2; uint32_t u; } c;
    c.h2 = h;
    return c.u;
}

__global__ __launch_bounds__(256, 4) void nei_attn_kernel(
    const float* __restrict__ x,
    const float* __restrict__ rel,
    const float* __restrict__ node,
    const float* __restrict__ W,
    const float* __restrict__ bias,
    float* __restrict__ out)
{
    __shared__ __align__(16) float lds_v[2][16][132];   // v[s][d], dbuf
    __shared__ __align__(16) float lds_alpha[2][16][4]; // [s][wv]
    __shared__ __align__(16) float lds_wgt[2][4][16];   // [wv][s]

    const int t    = threadIdx.x;
    const int lane = t & 63;
    const int wv   = t >> 6;        // wave owns d in [32wv, 32wv+32)
    const int l15  = lane & 15;
    const int quad = lane >> 4;

    // ---- W A-fragments: 48 VGPR/lane, loaded once ----
    // lane holds W[32wv + 16dt + l15][32q + 8quad + j], dt=0..1, q=0..5, j=0..7
    short8 wfrag[2][6];
    #pragma unroll
    for (int dt = 0; dt < 2; ++dt) {
        const float* wr = W + (size_t)(32 * wv + 16 * dt + l15) * 192 + quad * 8;
        #pragma unroll
        for (int q = 0; q < 6; ++q) {
            float4_t a = *(const float4_t*)(wr + 32 * q);
            float4_t b = *(const float4_t*)(wr + 32 * q + 4);
            union { uint32_t u[4]; short8 s; } f;
            f.u[0] = pk2bf(a.x, a.y); f.u[1] = pk2bf(a.z, a.w);
            f.u[2] = pk2bf(b.x, b.y); f.u[3] = pk2bf(b.z, b.w);
            wfrag[dt][q] = f.s;
        }
    }
    const float bias_l = bias[32 * wv + (lane & 31)];

    int tile = blockIdx.x * TILES_PER_BLK;

    // ---- prefetch tile 0: feat directly in B-frag order + x ----
    float4_t lda[6], ldb[6], xv0, xv1;
    {
        const float* fr = rel  + (size_t)tile * 1024 + l15 * 64  + quad * 8;
        const float* fn = node + (size_t)tile * 2048 + l15 * 128 + quad * 8;
        lda[0] = *(const float4_t*)(fr);       ldb[0] = *(const float4_t*)(fr + 4);
        lda[1] = *(const float4_t*)(fr + 32);  ldb[1] = *(const float4_t*)(fr + 36);
        lda[2] = *(const float4_t*)(fn);       ldb[2] = *(const float4_t*)(fn + 4);
        lda[3] = *(const float4_t*)(fn + 32);  ldb[3] = *(const float4_t*)(fn + 36);
        lda[4] = *(const float4_t*)(fn + 64);  ldb[4] = *(const float4_t*)(fn + 68);
        lda[5] = *(const float4_t*)(fn + 96);  ldb[5] = *(const float4_t*)(fn + 100);
        xv0 = *(const float4_t*)(x + (size_t)tile * 128 + 32 * wv + 4 * quad);
        xv1 = *(const float4_t*)(x + (size_t)tile * 128 + 32 * wv + 16 + 4 * quad);
    }

    for (int it = 0; it < TILES_PER_BLK; ++it) {
        const int buf = it & 1;

        // ---- cvt + MFMA: v[d][s] for this wave's 32 d ----
        float4_t acc0 = {0.f, 0.f, 0.f, 0.f};
        float4_t acc1 = {0.f, 0.f, 0.f, 0.f};
        #pragma unroll
        for (int q = 0; q < 6; ++q) {
            union { uint32_t u[4]; short8 s; } f;
            f.u[0] = pk2bf(lda[q].x, lda[q].y);
            f.u[1] = pk2bf(lda[q].z, lda[q].w);
            f.u[2] = pk2bf(ldb[q].x, ldb[q].y);
            f.u[3] = pk2bf(ldb[q].z, ldb[q].w);
            acc0 = __builtin_amdgcn_mfma_f32_16x16x32_bf16(wfrag[0][q], f.s, acc0, 0, 0, 0);
            acc1 = __builtin_amdgcn_mfma_f32_16x16x32_bf16(wfrag[1][q], f.s, acc1, 0, 0, 0);
        }
        // acc{dt}[r] = v_raw[d = 32wv + 16dt + 4quad + r][s = l15]  (bias deferred)

        // ---- alpha partial over this wave's 32 d ----
        float ap = xv0.x * acc0[0] + xv0.y * acc0[1] + xv0.z * acc0[2] + xv0.w * acc0[3]
                 + xv1.x * acc1[0] + xv1.y * acc1[1] + xv1.z * acc1[2] + xv1.w * acc1[3];
        ap += __shfl_xor(ap, 16);
        ap += __shfl_xor(ap, 32);
        if (quad == 0) lds_alpha[buf][l15][wv] = ap;

        // ---- v -> LDS (for the cross-d weighted sum) ----
        *(float4_t*)&lds_v[buf][l15][32 * wv + 4 * quad]      = acc0;
        *(float4_t*)&lds_v[buf][l15][32 * wv + 16 + 4 * quad] = acc1;

        __syncthreads();   // the only barrier: v + alpha partials ready

        // ---- prefetch next tile (issued AFTER barrier: never vmcnt-drained) ----
        if (it + 1 < TILES_PER_BLK) {
            const int nt = tile + 1;
            const float* fr = rel  + (size_t)nt * 1024 + l15 * 64  + quad * 8;
            const float* fn = node + (size_t)nt * 2048 + l15 * 128 + quad * 8;
            lda[0] = *(const float4_t*)(fr);       ldb[0] = *(const float4_t*)(fr + 4);
            lda[1] = *(const float4_t*)(fr + 32);  ldb[1] = *(const float4_t*)(fr + 36);
            lda[2] = *(const float4_t*)(fn);       ldb[2] = *(const float4_t*)(fn + 4);
            lda[3] = *(const float4_t*)(fn + 32);  ldb[3] = *(const float4_t*)(fn + 36);
            lda[4] = *(const float4_t*)(fn + 64);  ldb[4] = *(const float4_t*)(fn + 68);
            lda[5] = *(const float4_t*)(fn + 96);  ldb[5] = *(const float4_t*)(fn + 100);
            xv0 = *(const float4_t*)(x + (size_t)nt * 128 + 32 * wv + 4 * quad);
            xv1 = *(const float4_t*)(x + (size_t)nt * 128 + 32 * wv + 16 + 4 * quad);
        }

        // ---- softmax (per-lane, s = l15) ----
        float4_t apv = *(const float4_t*)&lds_alpha[buf][l15][0];
        const float alpha = (apv.x + apv.y + apv.z + apv.w) * 0.08838834764831845f;
        float mx = alpha;
        mx = fmaxf(mx, __shfl_xor(mx, 1));
        mx = fmaxf(mx, __shfl_xor(mx, 2));
        mx = fmaxf(mx, __shfl_xor(mx, 4));
        mx = fmaxf(mx, __shfl_xor(mx, 8));
        const float e = __expf(alpha - mx);
        float den = e;
        den += __shfl_xor(den, 1);
        den += __shfl_xor(den, 2);
        den += __shfl_xor(den, 4);
        den += __shfl_xor(den, 8);
        const float wgt = e / den;
        if (quad == 0) lds_wgt[buf][wv][l15] = wgt;   // intra-wave publish (lgkm order)

        // ---- out[d] = bias[d] + sum_s wgt[s] * v[s][d] ----
        // lane&31 -> d col; half-waves split s range; combine via xor 32
        const int dc = 32 * wv + (lane & 31);
        const int sh = (lane >> 5) * 8;               // 0 or 8
        float4_t wA = *(const float4_t*)&lds_wgt[buf][wv][sh];
        float4_t wB = *(const float4_t*)&lds_wgt[buf][wv][sh + 4];
        float o = wA.x * lds_v[buf][sh + 0][dc] + wA.y * lds_v[buf][sh + 1][dc]
                + wA.z * lds_v[buf][sh + 2][dc] + wA.w * lds_v[buf][sh + 3][dc]
                + wB.x * lds_v[buf][sh + 4][dc] + wB.y * lds_v[buf][sh + 5][dc]
                + wB.z * lds_v[buf][sh + 6][dc] + wB.w * lds_v[buf][sh + 7][dc];
        o += __shfl_xor(o, 32);
        if (lane < 32) out[(size_t)tile * 128 + dc] = o + bias_l;

        ++tile;
        // no trailing barrier: next tile writes buf^1; writes to THIS buf recur
        // only after the next tile's barrier, by which time these reads retired.
    }
}

extern "C" void kernel_launch(void* const* d_in, const int* in_sizes, int n_in,
                              void* d_out, int out_size, void* d_ws, size_t ws_size,
                              hipStream_t stream) {
    const float* x    = (const float*)d_in[0];
    const float* rel  = (const float*)d_in[1];
    const float* node = (const float*)d_in[2];
    const float* W    = (const float*)d_in[3];
    const float* bias = (const float*)d_in[4];
    float* out = (float*)d_out;
    hipLaunchKernelGGL(nei_attn_kernel, dim3(NBLK), dim3(256), 0, stream,
                       x, rel, node, W, bias, out);
}